// Round 1
// baseline (96.306 us; speedup 1.0000x reference)
//
#include <hip/hip_runtime.h>

#define NQ 5
#define DIM 32
#define NL 4
#define NFEAT 30

// ---------------------------------------------------------------------------
// Kernel 1: build the 32x32 circuit unitary from the 60 weight floats.
// Thread j evolves basis state e_j through the circuit entirely in registers
// (all loops fully unrolled so sre/sim indices are compile-time constants).
// Output layout: Ucr[j*32+z] = Re U[z][j], Uci[j*32+z] = Im U[z][j]
// (column-major, which is what the batched matvec consumes).
// ---------------------------------------------------------------------------
__global__ __launch_bounds__(64) void build_unitary(const float* __restrict__ W,
                                                    float* __restrict__ Ucr,
                                                    float* __restrict__ Uci) {
    const int j = threadIdx.x;
    if (j >= DIM) return;

    float sre[DIM], smi[DIM];
#pragma unroll
    for (int z = 0; z < DIM; ++z) { sre[z] = (z == j) ? 1.0f : 0.0f; smi[z] = 0.0f; }

#pragma unroll
    for (int l = 0; l < NL; ++l) {
        // --- Rot(phi, theta, omega) on each qubit ---
#pragma unroll
        for (int w = 0; w < NQ; ++w) {
            const float phi = W[(l * NQ + w) * 3 + 0];
            const float th  = W[(l * NQ + w) * 3 + 1];
            const float om  = W[(l * NQ + w) * 3 + 2];
            const float c = cosf(0.5f * th), s = sinf(0.5f * th);
            const float a  = 0.5f * (phi + om);
            const float bb = 0.5f * (phi - om);
            const float epr = cosf(a),  epi = -sinf(a);   // exp(-i a)
            const float emr = cosf(bb), emi = -sinf(bb);  // exp(-i b)
            // U = [[ep*c, -conj(em)*s], [em*s, conj(ep)*c]]
            const float u00r = epr * c,  u00i = epi * c;
            const float u01r = -emr * s, u01i = emi * s;
            const float u10r = emr * s,  u10i = emi * s;
            const float u11r = epr * c,  u11i = -epi * c;
            const int shift = 4 - w;  // qubit 0 = MSB of the 5-bit index
#pragma unroll
            for (int z0 = 0; z0 < DIM; ++z0) {
                if (((z0 >> shift) & 1) == 0) {
                    const int z1 = z0 | (1 << shift);
                    const float a0r = sre[z0], a0i = smi[z0];
                    const float a1r = sre[z1], a1i = smi[z1];
                    sre[z0] = u00r * a0r - u00i * a0i + u01r * a1r - u01i * a1i;
                    smi[z0] = u00r * a0i + u00i * a0r + u01r * a1i + u01i * a1r;
                    sre[z1] = u10r * a0r - u10i * a0i + u11r * a1r - u11i * a1i;
                    smi[z1] = u10r * a0i + u10i * a0r + u11r * a1i + u11i * a1r;
                }
            }
        }
        // --- CNOT ring: control w -> target (w + r) % NQ, r = (l % 4) + 1 ---
        const int r = (l % (NQ - 1)) + 1;
#pragma unroll
        for (int cq = 0; cq < NQ; ++cq) {
            const int tq = (cq + r) % NQ;
            const int cs = 4 - cq, ts = 4 - tq;
#pragma unroll
            for (int z = 0; z < DIM; ++z) {
                if ((((z >> cs) & 1) == 1) && (((z >> ts) & 1) == 0)) {
                    const int z1 = z | (1 << ts);
                    float t;
                    t = sre[z]; sre[z] = sre[z1]; sre[z1] = t;
                    t = smi[z]; smi[z] = smi[z1]; smi[z1] = t;
                }
            }
        }
    }

#pragma unroll
    for (int z = 0; z < DIM; ++z) {
        Ucr[j * DIM + z] = sre[z];
        Uci[j * DIM + z] = smi[z];
    }
}

// ---------------------------------------------------------------------------
// Kernel 2: per-sample  y = U x ; ev_w = (sum_z sign_w(z) |y_z|^2) / ||x||^2
// One sample per thread. x staged via LDS (coalesced load, padded stride 31).
// U read with uniform indices -> compiler scalarizes to s_load (SGPR operands).
// ---------------------------------------------------------------------------
__global__ __launch_bounds__(256) void qforward(const float* __restrict__ X,
                                                const float* __restrict__ Ucr,
                                                const float* __restrict__ Uci,
                                                float* __restrict__ out, int B) {
    __shared__ float xs[256 * 31];
    const int tid = threadIdx.x;
    const int b0  = blockIdx.x * 256;
    const int nrows = min(256, B - b0);
    const int tot = nrows * NFEAT;

    // coalesced stage: 7680 contiguous floats -> LDS rows of stride 31
    for (int k = tid; k < tot; k += 256) {
        const int row = k / NFEAT;
        const int col = k - row * NFEAT;
        xs[row * 31 + col] = X[(long)b0 * NFEAT + k];
    }
    __syncthreads();

    const int b = b0 + tid;

    float yre[DIM], yim[DIM];
#pragma unroll
    for (int z = 0; z < DIM; ++z) { yre[z] = 0.0f; yim[z] = 0.0f; }
    float n2 = 0.0f;

    for (int j = 0; j < NFEAT; ++j) {
        const float xj = xs[tid * 31 + j];
        n2 = fmaf(xj, xj, n2);
        const float* __restrict__ ur = Ucr + j * DIM;  // uniform address -> s_load
        const float* __restrict__ ui = Uci + j * DIM;
#pragma unroll
        for (int z = 0; z < DIM; ++z) {
            yre[z] = fmaf(ur[z], xj, yre[z]);
            yim[z] = fmaf(ui[z], xj, yim[z]);
        }
    }

    float p[DIM];
#pragma unroll
    for (int z = 0; z < DIM; ++z) p[z] = yre[z] * yre[z] + yim[z] * yim[z];

    const float inv = 1.0f / n2;

    float ev[NQ];
#pragma unroll
    for (int w = 0; w < NQ; ++w) ev[w] = 0.0f;
#pragma unroll
    for (int z = 0; z < DIM; ++z) {
#pragma unroll
        for (int w = 0; w < NQ; ++w) {
            if ((z >> (4 - w)) & 1) ev[w] -= p[z]; else ev[w] += p[z];
        }
    }

    __syncthreads();  // all threads done reading xs; safe to reuse
    if (b < B) {
#pragma unroll
        for (int w = 0; w < NQ; ++w) xs[tid * NQ + w] = ev[w] * inv;
    }
    __syncthreads();

    const int ototal = nrows * NQ;
    for (int k = tid; k < ototal; k += 256) {
        out[(long)b0 * NQ + k] = xs[k];
    }
}

extern "C" void kernel_launch(void* const* d_in, const int* in_sizes, int n_in,
                              void* d_out, int out_size, void* d_ws, size_t ws_size,
                              hipStream_t stream) {
    const float* X = (const float*)d_in[0];
    const float* W = (const float*)d_in[1];
    float* out = (float*)d_out;
    const int B = in_sizes[0] / NFEAT;

    float* Ucr = (float*)d_ws;
    float* Uci = Ucr + DIM * DIM;

    build_unitary<<<1, 64, 0, stream>>>(W, Ucr, Uci);

    const int nblocks = (B + 255) / 256;
    qforward<<<nblocks, 256, 0, stream>>>(X, Ucr, Uci, out, B);
}

// Round 2
// 55.443 us; speedup vs baseline: 1.7370x; 1.7370x over previous
//
#include <hip/hip_runtime.h>

#define NQ 5
#define DIM 32
#define NL 4
#define NFEAT 30
#define NGATES (NL * NQ)

// ---------------------------------------------------------------------------
// Kernel 1: build the 32x32 circuit unitary from the 60 weight floats.
// 1024 threads: thread t = (j,z) holds amplitude z of column j's state in
// 2 VGPRs. Gates mix amplitude pairs via __shfl_xor (width 32, so the two
// columns sharing a wave stay independent). The 20 2x2 gate matrices are
// precomputed into LDS by threads 0..19 (6 trig each) and broadcast-read.
// Output layout: Ucr[j*32+z] = Re U[z][j], Uci[j*32+z] = Im U[z][j].
// ---------------------------------------------------------------------------
__global__ __launch_bounds__(1024) void build_unitary(const float* __restrict__ W,
                                                      float* __restrict__ Ucr,
                                                      float* __restrict__ Uci) {
    __shared__ float g[NGATES][8];  // u00r,u00i,u01r,u01i,u10r,u10i,u11r,u11i

    const int t = threadIdx.x;
    if (t < NGATES) {
        const float phi = W[t * 3 + 0];
        const float th  = W[t * 3 + 1];
        const float om  = W[t * 3 + 2];
        const float c = cosf(0.5f * th), s = sinf(0.5f * th);
        const float a  = 0.5f * (phi + om);
        const float bb = 0.5f * (phi - om);
        const float epr = cosf(a),  epi = -sinf(a);   // exp(-i a)
        const float emr = cosf(bb), emi = -sinf(bb);  // exp(-i b)
        g[t][0] = epr * c;   g[t][1] = epi * c;    // u00 = ep*c
        g[t][2] = -emr * s;  g[t][3] = emi * s;    // u01 = -conj(em)*s
        g[t][4] = emr * s;   g[t][5] = emi * s;    // u10 = em*s
        g[t][6] = epr * c;   g[t][7] = -epi * c;   // u11 = conj(ep)*c
    }
    __syncthreads();

    const int j = t >> 5;       // column (initial basis state)
    const int z = t & 31;       // amplitude index this thread owns

    float ar = (z == j) ? 1.0f : 0.0f;
    float ai = 0.0f;

#pragma unroll
    for (int l = 0; l < NL; ++l) {
        // --- Rot on each qubit ---
#pragma unroll
        for (int w = 0; w < NQ; ++w) {
            const int gi = l * NQ + w;
            const int shift = 4 - w;          // qubit 0 = MSB
            const int msk = 1 << shift;
            const int bit = (z >> shift) & 1;
            const float pr = __shfl_xor(ar, msk, 32);
            const float pi = __shfl_xor(ai, msk, 32);
            // self coeff: bit ? u11 : u00 ; partner coeff: bit ? u10 : u01
            const float csr = bit ? g[gi][6] : g[gi][0];
            const float csi = bit ? g[gi][7] : g[gi][1];
            const float cpr = bit ? g[gi][4] : g[gi][2];
            const float cpi = bit ? g[gi][5] : g[gi][3];
            const float nar = csr * ar - csi * ai + cpr * pr - cpi * pi;
            const float nai = csr * ai + csi * ar + cpr * pi + cpi * pr;
            ar = nar; ai = nai;
        }
        // --- CNOT ring: control cq -> target (cq + r) % NQ ---
        const int r = (l % (NQ - 1)) + 1;
#pragma unroll
        for (int cq = 0; cq < NQ; ++cq) {
            const int tq = (cq + r) % NQ;
            const int cs = 4 - cq, ts = 4 - tq;
            const int tmask = 1 << ts;
            const float pr = __shfl_xor(ar, tmask, 32);
            const float pi = __shfl_xor(ai, tmask, 32);
            const int ctrl = (z >> cs) & 1;
            ar = ctrl ? pr : ar;
            ai = ctrl ? pi : ai;
        }
    }

    Ucr[t] = ar;   // t = j*32 + z, coalesced
    Uci[t] = ai;
}

// ---------------------------------------------------------------------------
// Kernel 2: per-sample  y = U x ; ev_w = (sum_z sign_w(z) |y_z|^2) / ||x||^2
// One sample per thread. x staged via LDS (coalesced load, padded stride 31).
// U read with uniform indices -> compiler scalarizes to s_load (SGPR operands).
// ---------------------------------------------------------------------------
__global__ __launch_bounds__(256) void qforward(const float* __restrict__ X,
                                                const float* __restrict__ Ucr,
                                                const float* __restrict__ Uci,
                                                float* __restrict__ out, int B) {
    __shared__ float xs[256 * 31];
    const int tid = threadIdx.x;
    const int b0  = blockIdx.x * 256;
    const int nrows = min(256, B - b0);
    const int tot = nrows * NFEAT;

    // coalesced stage: 7680 contiguous floats -> LDS rows of stride 31
    for (int k = tid; k < tot; k += 256) {
        const int row = k / NFEAT;
        const int col = k - row * NFEAT;
        xs[row * 31 + col] = X[(long)b0 * NFEAT + k];
    }
    __syncthreads();

    const int b = b0 + tid;

    float yre[DIM], yim[DIM];
#pragma unroll
    for (int z = 0; z < DIM; ++z) { yre[z] = 0.0f; yim[z] = 0.0f; }
    float n2 = 0.0f;

    for (int j = 0; j < NFEAT; ++j) {
        const float xj = xs[tid * 31 + j];
        n2 = fmaf(xj, xj, n2);
        const float* __restrict__ ur = Ucr + j * DIM;  // uniform address -> s_load
        const float* __restrict__ ui = Uci + j * DIM;
#pragma unroll
        for (int z = 0; z < DIM; ++z) {
            yre[z] = fmaf(ur[z], xj, yre[z]);
            yim[z] = fmaf(ui[z], xj, yim[z]);
        }
    }

    float p[DIM];
#pragma unroll
    for (int z = 0; z < DIM; ++z) p[z] = yre[z] * yre[z] + yim[z] * yim[z];

    const float inv = 1.0f / n2;

    float ev[NQ];
#pragma unroll
    for (int w = 0; w < NQ; ++w) ev[w] = 0.0f;
#pragma unroll
    for (int z = 0; z < DIM; ++z) {
#pragma unroll
        for (int w = 0; w < NQ; ++w) {
            if ((z >> (4 - w)) & 1) ev[w] -= p[z]; else ev[w] += p[z];
        }
    }

    __syncthreads();  // all threads done reading xs; safe to reuse
    if (b < B) {
#pragma unroll
        for (int w = 0; w < NQ; ++w) xs[tid * NQ + w] = ev[w] * inv;
    }
    __syncthreads();

    const int ototal = nrows * NQ;
    for (int k = tid; k < ototal; k += 256) {
        out[(long)b0 * NQ + k] = xs[k];
    }
}

extern "C" void kernel_launch(void* const* d_in, const int* in_sizes, int n_in,
                              void* d_out, int out_size, void* d_ws, size_t ws_size,
                              hipStream_t stream) {
    const float* X = (const float*)d_in[0];
    const float* W = (const float*)d_in[1];
    float* out = (float*)d_out;
    const int B = in_sizes[0] / NFEAT;

    float* Ucr = (float*)d_ws;
    float* Uci = Ucr + DIM * DIM;

    build_unitary<<<1, 1024, 0, stream>>>(W, Ucr, Uci);

    const int nblocks = (B + 255) / 256;
    qforward<<<nblocks, 256, 0, stream>>>(X, Ucr, Uci, out, B);
}

// Round 3
// 44.037 us; speedup vs baseline: 2.1869x; 1.2590x over previous
//
#include <hip/hip_runtime.h>

#define NQ 5
#define DIM 32
#define NL 4
#define NFEAT 30
#define NGATES (NL * NQ)

typedef float f32x2 __attribute__((ext_vector_type(2)));

// ---------------------------------------------------------------------------
// Kernel 1: build the 32x32 circuit unitary from the 60 weight floats.
// 1024 threads: thread t = (j,z) holds amplitude z of column j's state in
// 2 VGPRs. Gates mix amplitude pairs via __shfl_xor (width 32). The 20 2x2
// gate matrices are precomputed into LDS by threads 0..19.
// Output layout (interleaved, what the packed matvec wants):
//   Uc[j*64 + 2z + 0] = Re U[z][j],  Uc[j*64 + 2z + 1] = Im U[z][j]
// ---------------------------------------------------------------------------
__global__ __launch_bounds__(1024) void build_unitary(const float* __restrict__ W,
                                                      float* __restrict__ Uc) {
    __shared__ float g[NGATES][8];  // u00r,u00i,u01r,u01i,u10r,u10i,u11r,u11i

    const int t = threadIdx.x;
    if (t < NGATES) {
        const float phi = W[t * 3 + 0];
        const float th  = W[t * 3 + 1];
        const float om  = W[t * 3 + 2];
        const float c = cosf(0.5f * th), s = sinf(0.5f * th);
        const float a  = 0.5f * (phi + om);
        const float bb = 0.5f * (phi - om);
        const float epr = cosf(a),  epi = -sinf(a);   // exp(-i a)
        const float emr = cosf(bb), emi = -sinf(bb);  // exp(-i b)
        g[t][0] = epr * c;   g[t][1] = epi * c;    // u00 = ep*c
        g[t][2] = -emr * s;  g[t][3] = emi * s;    // u01 = -conj(em)*s
        g[t][4] = emr * s;   g[t][5] = emi * s;    // u10 = em*s
        g[t][6] = epr * c;   g[t][7] = -epi * c;   // u11 = conj(ep)*c
    }
    __syncthreads();

    const int z = t & 31;       // amplitude index this thread owns

    float ar = (z == (t >> 5)) ? 1.0f : 0.0f;  // column j = t>>5
    float ai = 0.0f;

#pragma unroll
    for (int l = 0; l < NL; ++l) {
        // --- Rot on each qubit ---
#pragma unroll
        for (int w = 0; w < NQ; ++w) {
            const int gi = l * NQ + w;
            const int shift = 4 - w;          // qubit 0 = MSB
            const int msk = 1 << shift;
            const int bit = (z >> shift) & 1;
            const float pr = __shfl_xor(ar, msk, 32);
            const float pi = __shfl_xor(ai, msk, 32);
            const float csr = bit ? g[gi][6] : g[gi][0];
            const float csi = bit ? g[gi][7] : g[gi][1];
            const float cpr = bit ? g[gi][4] : g[gi][2];
            const float cpi = bit ? g[gi][5] : g[gi][3];
            const float nar = csr * ar - csi * ai + cpr * pr - cpi * pi;
            const float nai = csr * ai + csi * ar + cpr * pi + cpi * pr;
            ar = nar; ai = nai;
        }
        // --- CNOT ring: control cq -> target (cq + r) % NQ ---
        const int r = (l % (NQ - 1)) + 1;
#pragma unroll
        for (int cq = 0; cq < NQ; ++cq) {
            const int tq = (cq + r) % NQ;
            const int cs = 4 - cq, ts = 4 - tq;
            const int tmask = 1 << ts;
            const float pr = __shfl_xor(ar, tmask, 32);
            const float pi = __shfl_xor(ai, tmask, 32);
            const int ctrl = (z >> cs) & 1;
            ar = ctrl ? pr : ar;
            ai = ctrl ? pi : ai;
        }
    }

    Uc[(t << 1) + 0] = ar;   // j*64 + 2z
    Uc[(t << 1) + 1] = ai;
}

// ---------------------------------------------------------------------------
// Kernel 2: per-sample  y = U x ; ev_w = (sum_z sign_w(z) |y_z|^2) / ||y||^2
// (U unitary => ||y|| == ||x||, so the norm is the butterfly's total sum.)
// One sample per thread. x staged via LDS (coalesced load, padded stride 31).
// U rows are wave-uniform -> s_load into SGPR pairs; 32 v_pk_fma_f32 per
// feature (packed re/im) with acc pinned in VGPRs by the asm constraints.
// ---------------------------------------------------------------------------
__global__ __launch_bounds__(256, 4) void qforward(const float* __restrict__ X,
                                                   const float* __restrict__ Uc,
                                                   float* __restrict__ out, int B) {
    __shared__ float xs[256 * 31];
    const int tid = threadIdx.x;
    const int b0  = blockIdx.x * 256;
    const int nrows = min(256, B - b0);
    const int tot = nrows * NFEAT;

    // coalesced stage: contiguous floats -> LDS rows of stride 31
    for (int k = tid; k < tot; k += 256) {
        const int row = k / NFEAT;
        const int col = k - row * NFEAT;
        xs[row * 31 + col] = X[(long)b0 * NFEAT + k];
    }
    __syncthreads();

    const int b = b0 + tid;

    f32x2 acc[DIM];
#pragma unroll
    for (int z = 0; z < DIM; ++z) acc[z] = (f32x2){0.0f, 0.0f};

    for (int j = 0; j < NFEAT; ++j) {
        const float xj = xs[tid * 31 + j];
        const f32x2 xx = {xj, xj};
        const f32x2* __restrict__ up = (const f32x2*)(Uc + j * (2 * DIM));  // uniform
#pragma unroll
        for (int z = 0; z < DIM; ++z) {
            const f32x2 u = up[z];
            asm("v_pk_fma_f32 %0, %1, %2, %0" : "+v"(acc[z]) : "s"(u), "v"(xx));
        }
    }

    // probabilities
    float q[DIM];
#pragma unroll
    for (int z = 0; z < DIM; ++z) q[z] = acc[z].x * acc[z].x + acc[z].y * acc[z].y;

    // 5-level signed-sum butterfly; level lev pairs over original bit lev
    // (bit0 = wire 4 ... bit4 = wire 0). Running sums collapse in place;
    // after the last level q[0] = total = ||y||^2 = ||x||^2.
    float evv[NQ];
#pragma unroll
    for (int lev = 0; lev < 5; ++lev) {
        const int n = DIM >> lev;
        float e = 0.0f;
#pragma unroll
        for (int k = 0; k < (DIM >> 1); ++k) {
            if (k < n / 2) {
                const float a = q[2 * k], d = q[2 * k + 1];
                q[k] = a + d;
                e += a - d;
            }
        }
        evv[4 - lev] = e;
    }
    const float inv = __builtin_amdgcn_rcpf(q[0]);

    __syncthreads();  // all threads done reading xs; safe to reuse
    if (b < B) {
#pragma unroll
        for (int w = 0; w < NQ; ++w) xs[tid * NQ + w] = evv[w] * inv;
    }
    __syncthreads();

    const int ototal = nrows * NQ;
    for (int k = tid; k < ototal; k += 256) {
        out[(long)b0 * NQ + k] = xs[k];
    }
}

extern "C" void kernel_launch(void* const* d_in, const int* in_sizes, int n_in,
                              void* d_out, int out_size, void* d_ws, size_t ws_size,
                              hipStream_t stream) {
    const float* X = (const float*)d_in[0];
    const float* W = (const float*)d_in[1];
    float* out = (float*)d_out;
    const int B = in_sizes[0] / NFEAT;

    float* Uc = (float*)d_ws;   // 2048 floats = 8 KB, interleaved (re,im)

    build_unitary<<<1, 1024, 0, stream>>>(W, Uc);

    const int nblocks = (B + 255) / 256;
    qforward<<<nblocks, 256, 0, stream>>>(X, Uc, out, B);
}

// Round 4
// 30.581 us; speedup vs baseline: 3.1493x; 1.4400x over previous
//
#include <hip/hip_runtime.h>

#define NQ 5
#define DIM 32
#define NL 4
#define NFEAT 30
#define NGATES (NL * NQ)

typedef float f32x4 __attribute__((ext_vector_type(4)));
typedef short bf16x8 __attribute__((ext_vector_type(8)));

// round-to-nearest-even f32 -> bf16
static __device__ __forceinline__ unsigned short f2bf(float f) {
    unsigned u = __float_as_uint(f);
    u += 0x7FFFu + ((u >> 16) & 1u);
    return (unsigned short)(u >> 16);
}

// ---------------------------------------------------------------------------
// Kernel 1: build the padded 64x32 bf16 matrix Upad from the 60 weights.
// Thread t=(j,z): amplitude z of column j's state in 2 VGPRs; gates mix
// pairs via __shfl_xor (width 32); gate matrices from LDS.
//   Upad[R][k]: R = 2z + (0:Re,1:Im)  (y-component row),  k = feature j.
//   y_z = sum_j U[z][j] x_j  -> row-major bf16, stride 32.
// ---------------------------------------------------------------------------
__global__ __launch_bounds__(1024) void build_unitary(const float* __restrict__ W,
                                                      unsigned short* __restrict__ Ubf) {
    __shared__ float g[NGATES][8];

    const int t = threadIdx.x;
    if (t < NGATES) {
        const float phi = W[t * 3 + 0];
        const float th  = W[t * 3 + 1];
        const float om  = W[t * 3 + 2];
        const float c = cosf(0.5f * th), s = sinf(0.5f * th);
        const float a  = 0.5f * (phi + om);
        const float bb = 0.5f * (phi - om);
        const float epr = cosf(a),  epi = -sinf(a);
        const float emr = cosf(bb), emi = -sinf(bb);
        g[t][0] = epr * c;   g[t][1] = epi * c;
        g[t][2] = -emr * s;  g[t][3] = emi * s;
        g[t][4] = emr * s;   g[t][5] = emi * s;
        g[t][6] = epr * c;   g[t][7] = -epi * c;
    }
    __syncthreads();

    const int j = t >> 5;
    const int z = t & 31;

    float ar = (z == j) ? 1.0f : 0.0f;
    float ai = 0.0f;

#pragma unroll
    for (int l = 0; l < NL; ++l) {
#pragma unroll
        for (int w = 0; w < NQ; ++w) {
            const int gi = l * NQ + w;
            const int shift = 4 - w;
            const int msk = 1 << shift;
            const int bit = (z >> shift) & 1;
            const float pr = __shfl_xor(ar, msk, 32);
            const float pi = __shfl_xor(ai, msk, 32);
            const float csr = bit ? g[gi][6] : g[gi][0];
            const float csi = bit ? g[gi][7] : g[gi][1];
            const float cpr = bit ? g[gi][4] : g[gi][2];
            const float cpi = bit ? g[gi][5] : g[gi][3];
            const float nar = csr * ar - csi * ai + cpr * pr - cpi * pi;
            const float nai = csr * ai + csi * ar + cpr * pi + cpi * pr;
            ar = nar; ai = nai;
        }
        const int r = (l % (NQ - 1)) + 1;
#pragma unroll
        for (int cq = 0; cq < NQ; ++cq) {
            const int tq = (cq + r) % NQ;
            const int cs = 4 - cq, ts = 4 - tq;
            const int tmask = 1 << ts;
            const float pr = __shfl_xor(ar, tmask, 32);
            const float pi = __shfl_xor(ai, tmask, 32);
            const int ctrl = (z >> cs) & 1;
            ar = ctrl ? pr : ar;
            ai = ctrl ? pi : ai;
        }
    }

    Ubf[(2 * z + 0) * 32 + j] = f2bf(ar);
    Ubf[(2 * z + 1) * 32 + j] = f2bf(ai);
}

// ---------------------------------------------------------------------------
// Kernel 2: MFMA batched matvec + expectation epilogue.
// Block = 256 threads = 4 waves, 256 samples. X tile staged->bf16 in LDS
// [sample][32] (features 30,31 zero). Per wave: 4 sample-tiles x 4 A-tiles
// of mfma_f32_16x16x32_bf16. D layout: col=lane&15=sample,
// row=(lane>>4)*4+reg -> each lane's 4 regs/tile = 2 complex amplitudes:
// z0 = 8t+2g (regs 0,1 = Re,Im), z1 = z0+1 (regs 2,3). Signed per-lane
// partials + shfl_xor(16,32) give the 5 PauliZ sums and the norm.
// ---------------------------------------------------------------------------
__global__ __launch_bounds__(256) void qforward(const float* __restrict__ X,
                                                const unsigned short* __restrict__ Ubf,
                                                float* __restrict__ out, int B) {
    __shared__ __align__(16) unsigned short xs[256 * 32];
    __shared__ float outbuf[256 * NQ];
    const int tid = threadIdx.x;
    const int b0  = blockIdx.x * 256;
    const int nrows = min(256, B - b0);
    const int tot = nrows * NFEAT;

    const int lane = tid & 63;
    const int g = lane >> 4;     // k-block / row-group within the MFMA
    const int r = lane & 15;     // A-row / B-col(sample) / D-col(sample)
    const int wv = tid >> 6;

    // A fragments: lane holds Upad[16t + r][8g .. 8g+7]
    bf16x8 afrag[4];
#pragma unroll
    for (int t = 0; t < 4; ++t)
        afrag[t] = *reinterpret_cast<const bf16x8*>(Ubf + (16 * t + r) * 32 + g * 8);

    // zero-pad features 30,31 of every LDS row (byte addr tid*64+60, 4B-aligned)
    *reinterpret_cast<unsigned int*>(&xs[tid * 32 + 30]) = 0u;

    // coalesced stage + f32->bf16 convert
    for (int k = tid; k < tot; k += 256) {
        const int row = k / NFEAT;
        const int col = k - row * NFEAT;
        xs[row * 32 + col] = f2bf(X[(long)b0 * NFEAT + k]);
    }
    __syncthreads();

    const float sg2 = (g & 2) ? -1.f : 1.f;   // wire2 sign: bit2 of z0 = g>>1
    const float sg3 = (g & 1) ? -1.f : 1.f;   // wire3 sign: bit1 of z0 = g&1

#pragma unroll
    for (int st = 0; st < 4; ++st) {
        const int srow = wv * 64 + st * 16 + r;   // this lane's sample in block
        const bf16x8 bfrag = *reinterpret_cast<const bf16x8*>(&xs[srow * 32 + g * 8]);

        f32x4 d[4];
#pragma unroll
        for (int t = 0; t < 4; ++t)
            d[t] = __builtin_amdgcn_mfma_f32_16x16x32_bf16(
                afrag[t], bfrag, (f32x4){0.f, 0.f, 0.f, 0.f}, 0, 0, 0);

        float ev0 = 0.f, ev1 = 0.f, ev2 = 0.f, ev3 = 0.f, ev4 = 0.f, nrm = 0.f;
#pragma unroll
        for (int t = 0; t < 4; ++t) {
            const float p0 = d[t].x * d[t].x + d[t].y * d[t].y;  // z0 = 8t+2g
            const float p1 = d[t].z * d[t].z + d[t].w * d[t].w;  // z1 = z0+1
            const float pt = p0 + p1;
            nrm += pt;
            ev0 += (t & 2) ? -pt : pt;        // wire0 = bit4 = t>>1
            ev1 += (t & 1) ? -pt : pt;        // wire1 = bit3 = t&1
            ev2 = fmaf(sg2, pt, ev2);         // wire2 = bit2 = g>>1
            ev3 = fmaf(sg3, pt, ev3);         // wire3 = bit1 = g&1
            ev4 += p0 - p1;                   // wire4 = bit0
        }
        // reduce over the 4 lane-groups (lane bits 4 and 5)
        ev0 += __shfl_xor(ev0, 16, 64); ev0 += __shfl_xor(ev0, 32, 64);
        ev1 += __shfl_xor(ev1, 16, 64); ev1 += __shfl_xor(ev1, 32, 64);
        ev2 += __shfl_xor(ev2, 16, 64); ev2 += __shfl_xor(ev2, 32, 64);
        ev3 += __shfl_xor(ev3, 16, 64); ev3 += __shfl_xor(ev3, 32, 64);
        ev4 += __shfl_xor(ev4, 16, 64); ev4 += __shfl_xor(ev4, 32, 64);
        nrm += __shfl_xor(nrm, 16, 64); nrm += __shfl_xor(nrm, 32, 64);

        if (g == 0) {
            const float inv = 1.0f / nrm;     // ||y||^2 == ||x||^2 (U unitary)
            const int s = wv * 64 + st * 16 + r;
            outbuf[s * NQ + 0] = ev0 * inv;
            outbuf[s * NQ + 1] = ev1 * inv;
            outbuf[s * NQ + 2] = ev2 * inv;
            outbuf[s * NQ + 3] = ev3 * inv;
            outbuf[s * NQ + 4] = ev4 * inv;
        }
    }

    __syncthreads();
    const int ototal = nrows * NQ;
    for (int k = tid; k < ototal; k += 256)
        out[(long)b0 * NQ + k] = outbuf[k];
}

extern "C" void kernel_launch(void* const* d_in, const int* in_sizes, int n_in,
                              void* d_out, int out_size, void* d_ws, size_t ws_size,
                              hipStream_t stream) {
    const float* X = (const float*)d_in[0];
    const float* W = (const float*)d_in[1];
    float* out = (float*)d_out;
    const int B = in_sizes[0] / NFEAT;

    unsigned short* Ubf = (unsigned short*)d_ws;   // 64x32 bf16 = 4 KB

    build_unitary<<<1, 1024, 0, stream>>>(W, Ubf);

    const int nblocks = (B + 255) / 256;
    qforward<<<nblocks, 256, 0, stream>>>(X, Ubf, out, B);
}

// Round 5
// 25.400 us; speedup vs baseline: 3.7916x; 1.2040x over previous
//
#include <hip/hip_runtime.h>

#define NQ 5
#define DIM 32
#define NL 4
#define NFEAT 30
#define NGATES (NL * NQ)

typedef float f32x4 __attribute__((ext_vector_type(4)));
typedef float f32x2 __attribute__((ext_vector_type(2)));
typedef short bf16x8 __attribute__((ext_vector_type(8)));

// round-to-nearest-even f32 -> bf16
static __device__ __forceinline__ unsigned short f2bf(float f) {
    unsigned u = __float_as_uint(f);
    u += 0x7FFFu + ((u >> 16) & 1u);
    return (unsigned short)(u >> 16);
}

// ---------------------------------------------------------------------------
// Kernel 1: build the padded 64x32 bf16 matrix Upad from the 60 weights.
// Thread t=(j,z): amplitude z of column j's state in 2 VGPRs; gates mix
// pairs via __shfl_xor (width 32); gate matrices from LDS.
//   Upad[R][k]: R = 2z + (0:Re,1:Im),  k = feature j.  Row-major bf16.
// ---------------------------------------------------------------------------
__global__ __launch_bounds__(1024) void build_unitary(const float* __restrict__ W,
                                                      unsigned short* __restrict__ Ubf) {
    __shared__ float g[NGATES][8];

    const int t = threadIdx.x;
    if (t < NGATES) {
        const float phi = W[t * 3 + 0];
        const float th  = W[t * 3 + 1];
        const float om  = W[t * 3 + 2];
        const float c = cosf(0.5f * th), s = sinf(0.5f * th);
        const float a  = 0.5f * (phi + om);
        const float bb = 0.5f * (phi - om);
        const float epr = cosf(a),  epi = -sinf(a);
        const float emr = cosf(bb), emi = -sinf(bb);
        g[t][0] = epr * c;   g[t][1] = epi * c;
        g[t][2] = -emr * s;  g[t][3] = emi * s;
        g[t][4] = emr * s;   g[t][5] = emi * s;
        g[t][6] = epr * c;   g[t][7] = -epi * c;
    }
    __syncthreads();

    const int j = t >> 5;
    const int z = t & 31;

    float ar = (z == j) ? 1.0f : 0.0f;
    float ai = 0.0f;

#pragma unroll
    for (int l = 0; l < NL; ++l) {
#pragma unroll
        for (int w = 0; w < NQ; ++w) {
            const int gi = l * NQ + w;
            const int shift = 4 - w;
            const int msk = 1 << shift;
            const int bit = (z >> shift) & 1;
            const float pr = __shfl_xor(ar, msk, 32);
            const float pi = __shfl_xor(ai, msk, 32);
            const float csr = bit ? g[gi][6] : g[gi][0];
            const float csi = bit ? g[gi][7] : g[gi][1];
            const float cpr = bit ? g[gi][4] : g[gi][2];
            const float cpi = bit ? g[gi][5] : g[gi][3];
            const float nar = csr * ar - csi * ai + cpr * pr - cpi * pi;
            const float nai = csr * ai + csi * ar + cpr * pi + cpi * pr;
            ar = nar; ai = nai;
        }
        const int r = (l % (NQ - 1)) + 1;
#pragma unroll
        for (int cq = 0; cq < NQ; ++cq) {
            const int tq = (cq + r) % NQ;
            const int cs = 4 - cq, ts = 4 - tq;
            const int tmask = 1 << ts;
            const float pr = __shfl_xor(ar, tmask, 32);
            const float pi = __shfl_xor(ai, tmask, 32);
            const int ctrl = (z >> cs) & 1;
            ar = ctrl ? pr : ar;
            ai = ctrl ? pi : ai;
        }
    }

    Ubf[(2 * z + 0) * 32 + j] = f2bf(ar);
    Ubf[(2 * z + 1) * 32 + j] = f2bf(ai);
}

// ---------------------------------------------------------------------------
// Kernel 2: MFMA batched matvec, B-fragments gathered DIRECTLY from global.
// Block = 256 threads = 4 waves = 256 samples. Lane (g = lane>>4, r = lane&15)
// of wave wv, sample-tile st owns sample srow = b0 + wv*64 + st*16 + r and
// features g*8..g*8+7: four 8B-aligned float2 loads (row stride 120 B), the
// last pair masked to 0 for g==3 (features 30,31). All 16 loads issued
// up-front; convert->MFMA->epilogue runs under them. No input LDS.
// D layout: col=lane&15=sample, row=(lane>>4)*4+reg; lane's 4 regs per
// A-tile t = 2 complex amplitudes z0=8t+2g (Re,Im), z1=z0+1.
// ---------------------------------------------------------------------------
__global__ __launch_bounds__(256) void qforward(const float* __restrict__ X,
                                                const unsigned short* __restrict__ Ubf,
                                                float* __restrict__ out, int B) {
    __shared__ float outbuf[256 * NQ];
    const int tid  = threadIdx.x;
    const int b0   = blockIdx.x * 256;
    const int lane = tid & 63;
    const int g    = lane >> 4;
    const int r    = lane & 15;
    const int wv   = tid >> 6;

    // A fragments: lane holds Upad[16t + r][g*8 .. g*8+7]
    bf16x8 afrag[4];
#pragma unroll
    for (int t = 0; t < 4; ++t)
        afrag[t] = *reinterpret_cast<const bf16x8*>(Ubf + (16 * t + r) * 32 + g * 8);

    // ---- issue all global loads up-front (16 float2 per thread) ----
    f32x2 raw[4][4];
#pragma unroll
    for (int st = 0; st < 4; ++st) {
        int srow = b0 + wv * 64 + st * 16 + r;
        srow = min(srow, B - 1);                       // safety clamp (B % 256 == 0)
        const float* rowp = X + (long)srow * NFEAT + g * 8;
        raw[st][0] = *reinterpret_cast<const f32x2*>(rowp + 0);
        raw[st][1] = *reinterpret_cast<const f32x2*>(rowp + 2);
        raw[st][2] = *reinterpret_cast<const f32x2*>(rowp + 4);
        raw[st][3] = (g == 3) ? (f32x2){0.f, 0.f}
                              : *reinterpret_cast<const f32x2*>(rowp + 6);
    }

    const float sg2 = (g & 2) ? -1.f : 1.f;   // wire2 sign: bit2 of z0
    const float sg3 = (g & 1) ? -1.f : 1.f;   // wire3 sign: bit1 of z0

#pragma unroll
    for (int st = 0; st < 4; ++st) {
        // convert this tile's 8 features to bf16
        bf16x8 bfrag;
#pragma unroll
        for (int q = 0; q < 4; ++q) {
            bfrag[2 * q + 0] = (short)f2bf(raw[st][q].x);
            bfrag[2 * q + 1] = (short)f2bf(raw[st][q].y);
        }

        f32x4 d[4];
#pragma unroll
        for (int t = 0; t < 4; ++t)
            d[t] = __builtin_amdgcn_mfma_f32_16x16x32_bf16(
                afrag[t], bfrag, (f32x4){0.f, 0.f, 0.f, 0.f}, 0, 0, 0);

        float ev0 = 0.f, ev1 = 0.f, ev2 = 0.f, ev3 = 0.f, ev4 = 0.f, nrm = 0.f;
#pragma unroll
        for (int t = 0; t < 4; ++t) {
            const float p0 = d[t].x * d[t].x + d[t].y * d[t].y;  // z0 = 8t+2g
            const float p1 = d[t].z * d[t].z + d[t].w * d[t].w;  // z1 = z0+1
            const float pt = p0 + p1;
            nrm += pt;
            ev0 += (t & 2) ? -pt : pt;        // wire0 = bit4 of z
            ev1 += (t & 1) ? -pt : pt;        // wire1 = bit3 of z
            ev2 = fmaf(sg2, pt, ev2);         // wire2 = bit2 of z
            ev3 = fmaf(sg3, pt, ev3);         // wire3 = bit1 of z
            ev4 += p0 - p1;                   // wire4 = bit0 of z
        }
        // reduce over lane bits 4,5 (the 4 g-groups)
        ev0 += __shfl_xor(ev0, 16, 64); ev0 += __shfl_xor(ev0, 32, 64);
        ev1 += __shfl_xor(ev1, 16, 64); ev1 += __shfl_xor(ev1, 32, 64);
        ev2 += __shfl_xor(ev2, 16, 64); ev2 += __shfl_xor(ev2, 32, 64);
        ev3 += __shfl_xor(ev3, 16, 64); ev3 += __shfl_xor(ev3, 32, 64);
        ev4 += __shfl_xor(ev4, 16, 64); ev4 += __shfl_xor(ev4, 32, 64);
        nrm += __shfl_xor(nrm, 16, 64); nrm += __shfl_xor(nrm, 32, 64);

        if (g == 0) {
            const float inv = 1.0f / nrm;     // ||y||^2 == ||x||^2 (U unitary)
            const int s = wv * 64 + st * 16 + r;
            outbuf[s * NQ + 0] = ev0 * inv;
            outbuf[s * NQ + 1] = ev1 * inv;
            outbuf[s * NQ + 2] = ev2 * inv;
            outbuf[s * NQ + 3] = ev3 * inv;
            outbuf[s * NQ + 4] = ev4 * inv;
        }
    }

    __syncthreads();
    const int nrows = min(256, B - b0);
    const int ototal = nrows * NQ;
    for (int k = tid; k < ototal; k += 256)
        out[(long)b0 * NQ + k] = outbuf[k];
}

extern "C" void kernel_launch(void* const* d_in, const int* in_sizes, int n_in,
                              void* d_out, int out_size, void* d_ws, size_t ws_size,
                              hipStream_t stream) {
    const float* X = (const float*)d_in[0];
    const float* W = (const float*)d_in[1];
    float* out = (float*)d_out;
    const int B = in_sizes[0] / NFEAT;

    unsigned short* Ubf = (unsigned short*)d_ws;   // 64x32 bf16 = 4 KB

    build_unitary<<<1, 1024, 0, stream>>>(W, Ubf);

    const int nblocks = (B + 255) / 256;
    qforward<<<nblocks, 256, 0, stream>>>(X, Ubf, out, B);
}